// Round 11
// baseline (249.031 us; speedup 1.0000x reference)
//
#include <hip/hip_runtime.h>
#include <stdint.h>
#include <math.h>

#define L_SEQ  4096
#define DMODEL 768
#define NHEADS 12
#define DKH    64
// 0.125 (=1/sqrt(64)) * log2(e): folded into Qp so p = exp2(S') needs no extra mul
#define QSCALE 0.18033688011112042f

typedef _Float16 f16;
typedef __attribute__((ext_vector_type(8))) _Float16 half8;
typedef __attribute__((ext_vector_type(4))) _Float16 half4;
typedef __attribute__((ext_vector_type(4))) float f32x4;
typedef __attribute__((ext_vector_type(16))) float f32x16;
typedef __attribute__((ext_vector_type(4))) unsigned int uint4v;

#define MFMA16(a, b, c) __builtin_amdgcn_mfma_f32_16x16x32_f16(a, b, c, 0, 0, 0)
#define MFMA32(a, b, c) __builtin_amdgcn_mfma_f32_32x32x16_f16(a, b, c, 0, 0, 0)

#define NE ((size_t)L_SEQ * DMODEL)      // 3,145,728
#define WE ((size_t)DMODEL * DMODEL)     // 589,824

static __device__ __forceinline__ unsigned int pack2(float a, float b) {
  return __builtin_bit_cast(unsigned int, __builtin_amdgcn_cvt_pkrtz(a, b));
}

// ---------------------------------------------------------------------------
// cvt_all: q,k,v (3*NE fp32) and Wq,Wk,Wv,Wo (4*WE fp32) -> f16.
// ---------------------------------------------------------------------------
__global__ __launch_bounds__(256)
void cvt_all(const float* __restrict__ q, const float* __restrict__ k,
             const float* __restrict__ v, const float* __restrict__ Wq,
             const float* __restrict__ Wk, const float* __restrict__ Wv,
             const float* __restrict__ Wo, f16* __restrict__ x16,
             f16* __restrict__ w16)
{
  const size_t NE4 = NE / 4, WE4 = WE / 4;
  size_t i = (size_t)blockIdx.x * 256 + threadIdx.x;
  const float* srcs[7] = {q, k, v, Wq, Wk, Wv, Wo};
  f16* dsts[7] = {x16, x16 + NE, x16 + 2 * NE,
                  w16, w16 + WE, w16 + 2 * WE, w16 + 3 * WE};
  const size_t sz4[7] = {NE4, NE4, NE4, WE4, WE4, WE4, WE4};
  int r = 0; size_t off = i;
  while (off >= sz4[r]) { off -= sz4[r]; ++r; }
  float4 f = reinterpret_cast<const float4*>(srcs[r])[off];
  half4 h; h[0] = (f16)f.x; h[1] = (f16)f.y; h[2] = (f16)f.z; h[3] = (f16)f.w;
  reinterpret_cast<half4*>(dsts[r])[off] = h;
}

// ---------------------------------------------------------------------------
// Unified big-tile GEMM: O[m,n] = sum_k A[m,k] * W[n,k] + bias[n], all f16 in,
// fp32 accumulate. Block 128x128, BK=64, 4 waves (2x2), wave tile 64x64 =
// 4 x mfma_f32_32x32x16 accs. Register-prefetch pipeline, padded LDS.
// KIND 0: fused QKV (blockIdx.x/6 selects matrix; Q scaled, V transposed)
// KIND 1: out-projection (fp32 output + bias)
// ---------------------------------------------------------------------------
template<int KIND>
__global__ __launch_bounds__(256)
void gemm_big(const f16* __restrict__ Abase, const f16* __restrict__ Wbase,
              const float* __restrict__ bq, const float* __restrict__ bk,
              const float* __restrict__ bv,
              f16* __restrict__ Qp, f16* __restrict__ Kp, f16* __restrict__ VpT,
              float* __restrict__ Ofp)
{
  __shared__ f16 As[128][72];
  __shared__ f16 Bs[128][72];
  const int tid  = threadIdx.x;
  const int lane = tid & 63, wid = tid >> 6;
  const int l31  = lane & 31, hc = lane >> 5;
  const int wm   = (wid & 1) * 64, wn = (wid >> 1) * 64;
  const int m0   = blockIdx.y * 128;

  int widx, n0;
  const f16 *A, *W;
  if (KIND == 0) {
    widx = blockIdx.x / 6;
    n0   = (blockIdx.x % 6) * 128;
    A = Abase + (size_t)widx * NE;
    W = Wbase + (size_t)widx * WE;
  } else {
    widx = 3;
    n0   = blockIdx.x * 128;
    A = Abase;
    W = Wbase;
  }

  // staging map: row = tid>>1 (0..127), seg = (tid&1)*32 -> 32 f16 = 4 half8
  const int srow = tid >> 1, sseg = (tid & 1) * 32;
  const f16* aptr = A + (size_t)(m0 + srow) * DMODEL + sseg;
  const f16* bptr = W + (size_t)(n0 + srow) * DMODEL + sseg;

  half8 ar[4], br[4];
#pragma unroll
  for (int t = 0; t < 4; ++t) {
    ar[t] = *reinterpret_cast<const half8*>(aptr + t * 8);
    br[t] = *reinterpret_cast<const half8*>(bptr + t * 8);
  }

  f32x16 acc[2][2] = {};

  for (int k0 = 0; k0 < DMODEL; k0 += 64) {
#pragma unroll
    for (int t = 0; t < 4; ++t) {
      *reinterpret_cast<half8*>(&As[srow][sseg + t * 8]) = ar[t];
      *reinterpret_cast<half8*>(&Bs[srow][sseg + t * 8]) = br[t];
    }
    __syncthreads();

    if (k0 + 64 < DMODEL) {       // prefetch next K-slab (overlaps MFMA)
#pragma unroll
      for (int t = 0; t < 4; ++t) {
        ar[t] = *reinterpret_cast<const half8*>(aptr + k0 + 64 + t * 8);
        br[t] = *reinterpret_cast<const half8*>(bptr + k0 + 64 + t * 8);
      }
    }

#pragma unroll
    for (int s = 0; s < 4; ++s) {
      half8 af[2], bf[2];
#pragma unroll
      for (int a = 0; a < 2; ++a)
        af[a] = *reinterpret_cast<half8*>(&As[wm + a * 32 + l31][s * 16 + hc * 8]);
#pragma unroll
      for (int b = 0; b < 2; ++b)
        bf[b] = *reinterpret_cast<half8*>(&Bs[wn + b * 32 + l31][s * 16 + hc * 8]);
#pragma unroll
      for (int a = 0; a < 2; ++a)
#pragma unroll
        for (int b = 0; b < 2; ++b)
          acc[a][b] = MFMA32(af[a], bf[b], acc[a][b]);
    }
    __syncthreads();
  }

  // ---- epilogue. C layout: col = l31, row = (r&3) + 8*(r>>2) + 4*hc
#pragma unroll
  for (int b = 0; b < 2; ++b) {
    const int gn = n0 + wn + b * 32 + l31;
    float bias;
    if (KIND == 0) bias = (widx == 0) ? bq[gn] : (widx == 1) ? bk[gn] : bv[gn];
    else           bias = bq[gn];     // bo passed via bq slot
#pragma unroll
    for (int a = 0; a < 2; ++a) {
      const int gmb = m0 + wm + a * 32 + 4 * hc;
      if (KIND == 1) {
#pragma unroll
        for (int r = 0; r < 16; ++r) {
          const int gm = gmb + (r & 3) + 8 * (r >> 2);
          Ofp[(size_t)gm * DMODEL + gn] = acc[a][b][r] + bias;
        }
      } else if (widx == 2) {           // V -> transposed (768, L), b64 packed
#pragma unroll
        for (int g = 0; g < 4; ++g) {
          half4 o4;
#pragma unroll
          for (int t = 0; t < 4; ++t) o4[t] = (f16)(acc[a][b][4 * g + t] + bias);
          *reinterpret_cast<half4*>(VpT + (size_t)gn * L_SEQ + gmb + 8 * g) = o4;
        }
      } else if (widx == 0) {           // Q row-major, pre-scaled
#pragma unroll
        for (int r = 0; r < 16; ++r) {
          const int gm = gmb + (r & 3) + 8 * (r >> 2);
          Qp[(size_t)gm * DMODEL + gn] = (f16)((acc[a][b][r] + bias) * QSCALE);
        }
      } else {                          // K row-major
#pragma unroll
        for (int r = 0; r < 16; ++r) {
          const int gm = gmb + (r & 3) + 8 * (r >> 2);
          Kp[(size_t)gm * DMODEL + gn] = (f16)(acc[a][b][r] + bias);
        }
      }
    }
  }
}

// ---------------------------------------------------------------------------
// Flash attention (unchanged from R10), 32x32x16 MFMA, no-max softmax,
// register-resident P.
// ---------------------------------------------------------------------------
__global__ __launch_bounds__(256, 3)
void attn_mfma4(const f16* __restrict__ Qp, const f16* __restrict__ Kp,
                const f16* __restrict__ VpT, f16* __restrict__ AO)
{
  const int h  = blockIdx.x;
  const int q0 = blockIdx.y * 64;
  const int tid  = threadIdx.x;
  const int lane = tid & 63, wid = tid >> 6;
  const int l31  = lane & 31, hc = lane >> 5;
  const int qh   = wid & 1, kh = wid >> 1;

  __shared__ __align__(16) char smem[25088];
  f16 (*Ks)[72] = (f16 (*)[72])smem;              // 64 x 72 f16 (key,d)
  f16 (*Vt)[72] = (f16 (*)[72])(smem + 9216);     // 64 x 72 f16 (d,key)
  float* Of  = (float*)smem;                      // epilogue alias
  float* lf  = (float*)(smem + 16384);
  f16*   Of16 = (f16*)(smem + 16640);

  half8 qf[4];
#pragma unroll
  for (int st = 0; st < 4; ++st)
    qf[st] = *reinterpret_cast<const half8*>(
        Qp + (size_t)(q0 + qh * 32 + l31) * DMODEL + h * DKH + st * 16 + hc * 8);

  f32x16 oacc[2] = {};
  float lsum = 0.0f;

  const int srow = tid >> 2, sseg = (tid & 3) * 16;
  const f16* kbase = Kp  + (size_t)srow * DMODEL + h * DKH + sseg;
  const f16* vbase = VpT + (size_t)(h * DKH + srow) * L_SEQ + sseg;

  half8 k0 = *reinterpret_cast<const half8*>(kbase);
  half8 k1 = *reinterpret_cast<const half8*>(kbase + 8);
  half8 v0 = *reinterpret_cast<const half8*>(vbase);
  half8 v1 = *reinterpret_cast<const half8*>(vbase + 8);

  for (int kt = 0; kt < L_SEQ; kt += 64) {
    *reinterpret_cast<half8*>(&Ks[srow][sseg])     = k0;
    *reinterpret_cast<half8*>(&Ks[srow][sseg + 8]) = k1;
    *reinterpret_cast<half8*>(&Vt[srow][sseg])     = v0;
    *reinterpret_cast<half8*>(&Vt[srow][sseg + 8]) = v1;
    __syncthreads();

    if (kt + 64 < L_SEQ) {
      const f16* kn = kbase + (size_t)(kt + 64) * DMODEL;
      const f16* vn = vbase + (kt + 64);
      k0 = *reinterpret_cast<const half8*>(kn);
      k1 = *reinterpret_cast<const half8*>(kn + 8);
      v0 = *reinterpret_cast<const half8*>(vn);
      v1 = *reinterpret_cast<const half8*>(vn + 8);
    }

    f32x16 s = {};
#pragma unroll
    for (int st = 0; st < 4; ++st) {
      half8 kf = *reinterpret_cast<half8*>(&Ks[kh * 32 + l31][st * 16 + hc * 8]);
      s = MFMA32(kf, qf[st], s);
    }

    unsigned int pk[8];
#pragma unroll
    for (int i = 0; i < 8; ++i) {
      float p0 = exp2f(s[2 * i]);
      float p1 = exp2f(s[2 * i + 1]);
      lsum += p0 + p1;
      pk[i] = pack2(p0, p1);
    }

    unsigned int recv[4];
#pragma unroll
    for (int j = 0; j < 4; ++j) {
      unsigned int sv = hc ? pk[(j & 1) + 4 * (j >> 1)]
                           : pk[2 + (j & 1) + 4 * (j >> 1)];
      recv[j] = (unsigned int)__shfl_xor((int)sv, 32);
    }

#pragma unroll
    for (int st = 0; st < 2; ++st) {
      uint4v pw;
#pragma unroll
      for (int t = 0; t < 4; ++t) {
        unsigned int h0v = (t < 2) ? pk[(t & 1) + 4 * st] : recv[2 * st + (t & 1)];
        unsigned int h1v = (t < 2) ? recv[2 * st + (t & 1)] : pk[(t & 1) + 4 * st + 2];
        pw[t] = hc ? h1v : h0v;
      }
      half8 pf = __builtin_bit_cast(half8, pw);
#pragma unroll
      for (int a = 0; a < 2; ++a) {
        half8 vf = *reinterpret_cast<half8*>(&Vt[a * 32 + l31][kh * 32 + st * 16 + hc * 8]);
        oacc[a] = MFMA32(vf, pf, oacc[a]);
      }
    }
    __syncthreads();
  }

  float lw = lsum + __shfl_xor(lsum, 32);

  if (kh == 0) {
#pragma unroll
    for (int a = 0; a < 2; ++a)
#pragma unroll
      for (int r = 0; r < 16; ++r) {
        int d = a * 32 + (r & 3) + 8 * (r >> 2) + 4 * hc;
        Of[((qh * 64) + d) * 32 + l31] = oacc[a][r];
      }
    if (lane < 32) lf[qh * 32 + l31] = lw;
  }
  __syncthreads();
  if (kh == 1) {
    const float inv = 1.0f / (lf[qh * 32 + l31] + lw);
#pragma unroll
    for (int a = 0; a < 2; ++a)
#pragma unroll
      for (int r = 0; r < 16; ++r) {
        int d = a * 32 + (r & 3) + 8 * (r >> 2) + 4 * hc;
        float val = (Of[((qh * 64) + d) * 32 + l31] + oacc[a][r]) * inv;
        Of16[(qh * 32 + l31) * 64 + d] = (f16)val;
      }
  }
  __syncthreads();

  *reinterpret_cast<half8*>(AO + (size_t)(q0 + srow) * DMODEL + h * DKH + sseg) =
      *reinterpret_cast<half8*>(&Of16[srow * 64 + sseg]);
  *reinterpret_cast<half8*>(AO + (size_t)(q0 + srow) * DMODEL + h * DKH + sseg + 8) =
      *reinterpret_cast<half8*>(&Of16[srow * 64 + sseg + 8]);
}

// ---------------------------------------------------------------------------
extern "C" void kernel_launch(void* const* d_in, const int* in_sizes, int n_in,
                              void* d_out, int out_size, void* d_ws, size_t ws_size,
                              hipStream_t stream) {
  const float* q  = (const float*)d_in[0];
  const float* k  = (const float*)d_in[1];
  const float* v  = (const float*)d_in[2];
  const float* Wq = (const float*)d_in[3];
  const float* bq = (const float*)d_in[4];
  const float* Wk = (const float*)d_in[5];
  const float* bk = (const float*)d_in[6];
  const float* Wv = (const float*)d_in[7];
  const float* bv = (const float*)d_in[8];
  const float* Wo = (const float*)d_in[9];
  const float* bo = (const float*)d_in[10];
  float* out = (float*)d_out;

  f16* x16 = (f16*)d_ws;          // 3*NE
  f16* w16 = x16 + 3 * NE;        // 4*WE
  f16* Qp  = w16 + 4 * WE;        // NE, pre-scaled
  f16* Kp  = Qp + NE;             // NE
  f16* VpT = Kp + NE;             // NE (768, L)
  f16* AO  = VpT + NE;            // NE
  // total 48.8 MB

  const int ncvt = (int)((3 * (NE / 4) + 4 * (WE / 4)) / 256);
  cvt_all<<<ncvt, 256, 0, stream>>>(q, k, v, Wq, Wk, Wv, Wo, x16, w16);

  dim3 gqkv(18, L_SEQ / 128);                       // 576 blocks
  gemm_big<0><<<gqkv, 256, 0, stream>>>(x16, w16, bq, bk, bv,
                                        Qp, Kp, VpT, nullptr);

  dim3 gattn(NHEADS, L_SEQ / 64);                   // 768 blocks
  attn_mfma4<<<gattn, 256, 0, stream>>>(Qp, Kp, VpT, AO);

  dim3 gout(DMODEL / 128, L_SEQ / 128);             // 192 blocks
  gemm_big<1><<<gout, 256, 0, stream>>>(AO, w16 + 3 * WE, bo, nullptr, nullptr,
                                        nullptr, nullptr, nullptr, out);
}